// Round 1
// baseline (63.305 us; speedup 1.0000x reference)
//
#include <hip/hip_runtime.h>
#include <math.h>

// ---------------- constants ----------------
#define PI_F 3.14159265358979323846f
__device__ __constant__ float kLOG_2PI = 1.8378770664093453f;   // fl32(log(2pi))
__device__ __constant__ float kPI_8    = 0.39269908169872414f;  // fl32(pi/8)
__device__ __constant__ float kTWO_PI  = 6.283185307179586f;    // fl32(2pi)
#define INV_2PI_D 0.15915494309189535  // 1/(2pi) in double

// =====================================================================
// FFT: 1024-point radix-2 DIT, one wave per row, 16 complex elems/lane.
// Layout L1: e = lane*16 + r      (stages s=1,2,4,8   : r-local)
// Layout L3: e = (lane>>4)*256 + r*16 + (lane&15)
//                                  (stages s=16..128  : r-local)
// Layout L2: e = r*64 + lane      (stages s=256,512   : r-local)
// Transposes via padded LDS (a -> a + (a>>5)): max 2-way bank alias (free).
// =====================================================================
__global__ __launch_bounds__(256) void fft_kernel(
    const float* __restrict__ xre, const float* __restrict__ xim,
    float* __restrict__ yre, float* __restrict__ yim)
{
    __shared__ float lre[4][1056];
    __shared__ float lim[4][1056];

    const int lane = threadIdx.x & 63;
    const int wid  = threadIdx.x >> 6;
    const int row  = (blockIdx.x << 2) | wid;
    const size_t base = (size_t)row << 10;

    float re[16], im[16];

    // ---- load, bit-reversed, L1 layout ----
    const int rev6l = __brev((unsigned)lane) >> 26;
    const int REV4[16] = {0,8,4,12,2,10,6,14,1,9,5,13,3,11,7,15};
#pragma unroll
    for (int r = 0; r < 16; ++r) {
        const int a = REV4[r] * 64 + rev6l;   // within one 256B window per r
        re[r] = xre[base + a];
        im[r] = xim[base + a];
    }

    // ---- L1 stages: s = 1,2,4,8 ; twiddle k = r&(s-1), constants ----
    const float W8R[8] = {1.f, 0.9238795325112867f, 0.7071067811865476f,
                          0.3826834323650898f, 0.f, -0.3826834323650898f,
                          -0.7071067811865476f, -0.9238795325112867f};
    const float W8I[8] = {0.f, -0.3826834323650898f, -0.7071067811865476f,
                          -0.9238795325112867f, -1.f, -0.9238795325112867f,
                          -0.7071067811865476f, -0.3826834323650898f};
#pragma unroll
    for (int st = 0; st < 4; ++st) {
        const int S = 1 << st;
#pragma unroll
        for (int rl = 0; rl < 16; ++rl) {
            if (rl & S) continue;
            const int rh = rl | S;
            const int k8 = (rl & (S - 1)) * (8 >> st);
            const float wr = W8R[k8], wi = W8I[k8];
            const float tr = wr * re[rh] - wi * im[rh];
            const float ti = wr * im[rh] + wi * re[rh];
            re[rh] = re[rl] - tr;  im[rh] = im[rl] - ti;
            re[rl] += tr;          im[rl] += ti;
        }
    }

    float* sre = lre[wid];
    float* sim = lim[wid];

    // ---- T1: L1 -> L3 ----
#pragma unroll
    for (int r = 0; r < 16; ++r) {
        int a = lane * 16 + r; a += a >> 5;
        sre[a] = re[r]; sim[a] = im[r];
    }
    __syncthreads();
#pragma unroll
    for (int r = 0; r < 16; ++r) {
        const int e = ((lane >> 4) << 8) + (r << 4) + (lane & 15);
        const int a = e + (e >> 5);
        re[r] = sre[a]; im[r] = sim[a];
    }

    // ---- L3 stages: s = 16,32,64,128 ; k = (rl&(S-1))*16 + (lane&15) ----
#pragma unroll
    for (int st = 0; st < 4; ++st) {
        const int S = 1 << st;
        const float cmul = -PI_F / (float)(16 << st);   // fl32(-pi/s), exact /2^n
#pragma unroll
        for (int rl = 0; rl < 16; ++rl) {
            if (rl & S) continue;
            const int rh = rl | S;
            const int k = ((rl & (S - 1)) << 4) + (lane & 15);
            const float ang = cmul * (float)k;
            float wi, wr;
            __sincosf(ang, &wi, &wr);
            const float tr = wr * re[rh] - wi * im[rh];
            const float ti = wr * im[rh] + wi * re[rh];
            re[rh] = re[rl] - tr;  im[rh] = im[rl] - ti;
            re[rl] += tr;          im[rl] += ti;
        }
    }

    __syncthreads();
    // ---- T2: L3 -> L2 ----
#pragma unroll
    for (int r = 0; r < 16; ++r) {
        const int e = ((lane >> 4) << 8) + (r << 4) + (lane & 15);
        const int a = e + (e >> 5);
        sre[a] = re[r]; sim[a] = im[r];
    }
    __syncthreads();
#pragma unroll
    for (int r = 0; r < 16; ++r) {
        const int e = (r << 6) + lane;
        const int a = e + (e >> 5);
        re[r] = sre[a]; im[r] = sim[a];
    }

    // ---- L2 stages: s = 256 (S=4), 512 (S=8) ; k = (rl&(S-1))*64 + lane ----
#pragma unroll
    for (int st = 2; st < 4; ++st) {
        const int S = 1 << st;
        const float cmul = -PI_F / (float)(64 << st);
#pragma unroll
        for (int rl = 0; rl < 16; ++rl) {
            if (rl & S) continue;
            const int rh = rl | S;
            const int k = ((rl & (S - 1)) << 6) + lane;
            const float ang = cmul * (float)k;
            float wi, wr;
            __sincosf(ang, &wi, &wr);
            const float tr = wr * re[rh] - wi * im[rh];
            const float ti = wr * im[rh] + wi * re[rh];
            re[rh] = re[rl] - tr;  im[rh] = im[rl] - ti;
            re[rl] += tr;          im[rl] += ti;
        }
    }

    // ---- store, coalesced ----
#pragma unroll
    for (int r = 0; r < 16; ++r) {
        yre[base + (r << 6) + lane] = re[r];
        yim[base + (r << 6) + lane] = im[r];
    }
}

// =====================================================================
// Riemann-Siegel Z(t): replicate reference float32 phase semantics
// (explicit _rn ops, no contraction), CR log tables (double-computed),
// accurate cos via double range-reduction to revolutions + v_cos_f32.
// =====================================================================
__global__ __launch_bounds__(256) void z_kernel(
    const float* __restrict__ tin, float* __restrict__ zout, int n)
{
    __shared__ float slog[1024];
    __shared__ float srsq[1024];
    for (int i = threadIdx.x; i < 1024; i += 256) {
        const double nd = (double)(i + 1);
        slog[i] = (float)log(nd);            // correctly-rounded fl32(log n)
        srsq[i] = (float)(1.0 / sqrt(nd));
    }
    __syncthreads();

    const int gid = blockIdx.x * 256 + threadIdx.x;
    if (gid >= n) return;

    const float t  = tin[gid];
    const float th = __fmul_rn(t, 0.5f);
    const float logt = (float)log((double)t);          // CR fl32(log t)
    float theta = __fsub_rn(__fsub_rn(__fmul_rn(th, __fsub_rn(logt, kLOG_2PI)), th), kPI_8);
    theta = __fadd_rn(theta, __fdiv_rn(1.0f, __fmul_rn(48.0f, t)));

    int nt = (int)sqrtf(__fdiv_rn(t, kTWO_PI));
    nt = min(max(nt, 10), 1024);

    float acc = 0.0f;
    for (int i = 0; i < nt; ++i) {
        // phases = fl32( fl32(t * log_n) - theta )  -- matches reference
        const float p = __fsub_rn(__fmul_rn(t, slog[i]), theta);
        // accurate cos(p): double reduction to revolutions, hw cos(2*pi*x)
        const double rev = (double)p * INV_2PI_D;
        const double fr  = rev - rint(rev);            // |fr| <= 0.5
        const float  c   = __builtin_amdgcn_cosf((float)fr);
        acc = __fmaf_rn(srsq[i], c, acc);
    }
    zout[gid] = __fmul_rn(2.0f, acc);
}

extern "C" void kernel_launch(void* const* d_in, const int* in_sizes, int n_in,
                              void* d_out, int out_size, void* d_ws, size_t ws_size,
                              hipStream_t stream)
{
    const float* xre = (const float*)d_in[0];
    const float* xim = (const float*)d_in[1];
    const float* t   = (const float*)d_in[2];

    const size_t nfft = (size_t)in_sizes[0];          // 16384*1024
    const int nrows = (int)(nfft >> 10);              // 16384
    const int nt    = in_sizes[2];                    // 262144

    float* yre = (float*)d_out;
    float* yim = yre + nfft;
    float* z   = yre + 2 * nfft;

    fft_kernel<<<nrows / 4, 256, 0, stream>>>(xre, xim, yre, yim);
    z_kernel<<<(nt + 255) / 256, 256, 0, stream>>>(t, z, nt);
}